// Round 3
// baseline (235.928 us; speedup 1.0000x reference)
//
#include <hip/hip_runtime.h>
#include <stdint.h>

// out[b,s,d] = x[b,s,d] + pe[s,d]
//   pe[s,d] = (d even) ? sin(s * inv_freq(d)) : cos(s * inv_freq(d))
//   inv_freq(d) = 10000^(-2d/1024) = exp2(-d * log2(10000)/512)
// Shape (8, 4096, 1024), n = 33,554,432 elements.
//
// Dtype-adaptive: a detect kernel classifies d_in[0] as bf16 vs fp32 by
// examining the leading 256 uint16s (bf16 N(0,1) data has biased exponents
// confined to ~[110,129]; fp32 low-halves are random mantissa bits with
// uniform exponents -> P(misclassify) ~ 1e-102). Flag lives in d_ws.

#define D_MODEL 1024
#define C_FREQ (-0.025952563241307517f)   /* -log2(10000)/512 */

__device__ float pe_val(int s, int d) {
    float angle = (float)s * exp2f(C_FREQ * (float)d);
    return (d & 1) ? cosf(angle) : sinf(angle);   // accurate libm range reduction
}

__device__ uint32_t f2bf_rne(float f) {           // fp32 -> bf16 bits, round-nearest-even
    uint32_t b = __float_as_uint(f);
    return (b + 0x7FFFu + ((b >> 16) & 1u)) >> 16;
}

__global__ void detect_kernel(const uint16_t* in, int* flag) {
    __shared__ int bad;
    if (threadIdx.x == 0) bad = 0;
    __syncthreads();
    uint16_t u = in[threadIdx.x];                 // 256 threads, 256 uint16s
    int e = (u >> 7) & 0xFF;
    if (!(e == 0 || (e >= 96 && e <= 135))) bad = 1;
    __syncthreads();
    if (threadIdx.x == 0) *flag = (bad ? 0 : 1);  // 1 = bf16, 0 = fp32
}

__global__ void pe_kernel(const void* vin, void* vout, const int* flag, int n) {
    __shared__ int bf16_s;
    if (threadIdx.x == 0) bf16_s = *flag;
    __syncthreads();
    const int is_bf16 = bf16_s;                   // uniform branch
    const int tid = blockIdx.x * blockDim.x + threadIdx.x;
    const int nth = gridDim.x * blockDim.x;

    if (is_bf16) {
        const uint32_t* in = (const uint32_t*)vin;
        uint32_t* out = (uint32_t*)vout;
        const int nw = n >> 1;                    // 2 bf16 per 32-bit word
        for (int i = tid; i < nw; i += nth) {
            const int e0 = i << 1;                // flat element index (even)
            const int d = e0 & (D_MODEL - 1);     // even -> sin; d+1 odd -> cos
            const int s = (e0 >> 10) & 4095;
            const float p0 = pe_val(s, d);
            const float p1 = pe_val(s, d + 1);
            const uint32_t w = in[i];
            const float x0 = __uint_as_float((w & 0xFFFFu) << 16);
            const float x1 = __uint_as_float(w & 0xFFFF0000u);
            out[i] = f2bf_rne(x0 + p0) | (f2bf_rne(x1 + p1) << 16);
        }
    } else {
        const float* in = (const float*)vin;
        float* out = (float*)vout;
        for (int i = tid; i < n; i += nth) {
            const int d = i & (D_MODEL - 1);
            const int s = (i >> 10) & 4095;
            out[i] = in[i] + pe_val(s, d);
        }
    }
}

extern "C" void kernel_launch(void* const* d_in, const int* in_sizes, int n_in,
                              void* d_out, int out_size, void* d_ws, size_t ws_size,
                              hipStream_t stream) {
    const void* x = d_in[0];
    int* flag = (int*)d_ws;
    detect_kernel<<<1, 256, 0, stream>>>((const uint16_t*)x, flag);
    pe_kernel<<<4096, 256, 0, stream>>>(x, d_out, flag, out_size);
}

// Round 4
// 231.009 us; speedup vs baseline: 1.0213x; 1.0213x over previous
//
#include <hip/hip_runtime.h>
#include <stdint.h>

// out[b,s,d] = x[b,s,d] + pe[s,d]   (fp32 in/out — proven by WRITE_SIZE=134MB in R3)
//   pe[s,d] = (d even) ? sin(s * 10000^(-2d/1024)) : cos(s * 10000^(-2d/1024))
// Shape (8, 4096, 1024). Traffic: 134 MB read + 134 MB write -> ~43 us @ 6.3 TB/s
// (less if L3 holds the input from the harness's restore copy).
//
// R3 was VALU-bound (60% VALUBusy): per-element libm sin/cos. Fix: one thread
// owns a float4 of dims at one s and loops over all 8 batches -> PE computed
// once per 32 output elements (4 transcendental pairs amortized 8x), with 8
// independent load/add/store chains for ILP.

constexpr int MODEL_DIM = 1024;
constexpr int SEQ = 4096;
constexpr int BATCH = 8;
constexpr int SD = SEQ * MODEL_DIM;           // 4,194,304
constexpr float C_FREQ = -0.025952563241307517f;  // -log2(10000)/512

typedef float v4f __attribute__((ext_vector_type(4)));

__global__ __launch_bounds__(256) void pe_add_kernel(
    const float* __restrict__ xin, float* __restrict__ xout)
{
    const int t = blockIdx.x * blockDim.x + threadIdx.x;  // 0 .. SD/4-1
    const int s = t >> 8;                 // 256 float4 vectors per seq position
    const int dbase = (t & 255) << 2;     // starting dim, multiple of 4 (even)

    const float pos = (float)s;
    float pe[4];
#pragma unroll
    for (int j = 0; j < 4; ++j) {
        const float angle = pos * exp2f(C_FREQ * (float)(dbase + j));
        pe[j] = (j & 1) ? cosf(angle) : sinf(angle);  // accurate range reduction
    }
    v4f pv;
    pv.x = pe[0]; pv.y = pe[1]; pv.z = pe[2]; pv.w = pe[3];

    const size_t base = (size_t)t * 4;
#pragma unroll
    for (int b = 0; b < BATCH; ++b) {
        const size_t off = (size_t)b * (size_t)SD + base;
        v4f x = __builtin_nontemporal_load((const v4f*)(xin + off));  // read-once
        x += pv;
        __builtin_nontemporal_store(x, (v4f*)(xout + off));           // write-only
    }
}

extern "C" void kernel_launch(void* const* d_in, const int* in_sizes, int n_in,
                              void* d_out, int out_size, void* d_ws, size_t ws_size,
                              hipStream_t stream) {
    const float* x = (const float*)d_in[0];
    float* out = (float*)d_out;
    const int threads = 256;
    const int blocks = (SD / 4) / threads;   // 4096 blocks, exact cover
    pe_add_kernel<<<blocks, threads, 0, stream>>>(x, out);
}